// Round 5
// baseline (117.476 us; speedup 1.0000x reference)
//
#include <hip/hip_runtime.h>
#include <hip/hip_bf16.h>

#define NB 16
#define NA 128
#define HD 256
#define EF 30

#define SELU_SCALE 1.0507009873554805f
#define SELU_AS    1.7580993408473766f   // scale * alpha

typedef __attribute__((ext_vector_type(8))) short bf16x8;
typedef __attribute__((ext_vector_type(4))) float f32x4;

__device__ __forceinline__ unsigned short f2u16(float x) {
    union { __hip_bfloat16 b; unsigned short u; } cv;
    cv.b = __float2bfloat16(x);   // RNE
    return cv.u;
}
__device__ __forceinline__ short f2s16(float x) { return (short)f2u16(x); }

__device__ __forceinline__ float selu_f(float s) {
    float pos = SELU_SCALE * s;
    float neg = fmaf(SELU_AS, __expf(s), -SELU_AS);
    return s > 0.f ? pos : neg;
}

// -----------------------------------------------------------------------------
// ws layout (ws = 256 MiB, poisoned 0xAA each call; we rewrite all we read):
//   [0, 1MB)              h1A   : h1 in MFMA A-frag layout [m][s][lane][8] bf16
//   [1MB, +16KB)          WfFrag: [t][lane][8] bf16 (k padded 30->32)
//   [1MB+16KB, +256KB)    WwFrag: [t][s][lane][8] bf16
//   [1MB+272KB, +1MB)     hA    : h in MFMA A-frag layout [m][s][lane][8] bf16
// A-frag (16x16x32): lane holds A[i][k], i = lane&15, k = (lane>>4)*8 + e.
// B-frag:            lane holds B[k][j], j = lane&15, k = (lane>>4)*8 + e.
// -----------------------------------------------------------------------------

__global__ __launch_bounds__(256)
void efconv_prep(const float* __restrict__ Wf, const float* __restrict__ Ww,
                 const float* __restrict__ h,
                 unsigned short* __restrict__ WfFragU,
                 unsigned short* __restrict__ WwFragU,
                 unsigned short* __restrict__ hAU)
{
    const int idx = blockIdx.x * 256 + threadIdx.x;
    if (idx < 16*64*8) {                              // WfFrag: 8192
        const int e = idx & 7, lane = (idx >> 3) & 63, t = idx >> 9;
        const int f = t*16 + (lane & 15);
        const int k = ((lane >> 4) << 3) + e;
        WfFragU[idx] = f2u16((k < EF) ? Wf[f*EF + k] : 0.f);
    }
    const int jdx = idx - 16*64*8;
    if (jdx >= 0 && jdx < 16*16*64*8) {               // WwFrag: 131072
        const int e = jdx & 7, lane = (jdx >> 3) & 63;
        const int s = (jdx >> 9) & 15, t = jdx >> 13;
        const int f = t*16 + (lane & 15);
        const int k = s*32 + ((lane >> 4) << 3) + e;
        WwFragU[jdx] = f2u16(Ww[f*(2*HD) + k]);
    }
    const int kdx = idx - 16*64*8 - 16*16*64*8;
    if (kdx >= 0 && kdx < 128*8*64*8) {               // hA: 524288
        const int e = kdx & 7, lane = (kdx >> 3) & 63;
        const int s = (kdx >> 9) & 7, m = kdx >> 12;
        const int row = m*16 + (lane & 15);
        const int k = s*32 + ((lane >> 4) << 3) + e;
        hAU[kdx] = f2u16(h[row*HD + k]);
    }
}

// -----------------------------------------------------------------------------
// Stage 1: per (b,i) block (2048 blocks, 4 waves). e[bi] staged once through
// LDS with a coalesced float4 load; A-frags built from aligned ds_read_b64
// (row stride 30 dwords spreads banks; k=30,31 pad via two cndmasks).
// Wave w owns f-tiles 4w..4w+3 (Bf frags + bias in regs). Fused SELU *
// edge_mask * h j-reduction into 4 partials; shfl_xor(16,32) finishes j-sum;
// h1 stored directly in stage-2 A-frag layout. One barrier total.
// -----------------------------------------------------------------------------
__global__ __launch_bounds__(256, 4)
void efconv_stage1(const float* __restrict__ e, const float* __restrict__ h,
                   const float* __restrict__ em, const float* __restrict__ bf,
                   const bf16x8* __restrict__ WfFrag,
                   unsigned short* __restrict__ h1A)
{
    __shared__ float elds[NA * EF];      // 3840 floats = 15.4 KB

    const int bi   = blockIdx.x;
    const int b    = bi >> 7;
    const int tid  = threadIdx.x;
    const int wid  = tid >> 6;
    const int lane = tid & 63;
    const int l15  = lane & 15;
    const int lq   = lane >> 4;
    const int k0   = lq * 8;

    // coalesced stage of e[bi] (960 float4)
    {
        const float4* __restrict__ src = reinterpret_cast<const float4*>(e + (size_t)bi * (NA*EF));
        float4* dst = reinterpret_cast<float4*>(elds);
        for (int it = tid; it < 960; it += 256) dst[it] = src[it];
    }
    __syncthreads();

    bf16x8 Bf[4];
    float bias[4];
#pragma unroll
    for (int n = 0; n < 4; ++n) {
        const int t = wid*4 + n;
        Bf[n]   = WfFrag[t*64 + lane];
        bias[n] = bf[t*16 + l15];
    }

    const float* __restrict__ em_row = em + (size_t)bi * NA;
    const float* __restrict__ hb     = h  + (size_t)b  * (NA*HD);
    const bool ktail = (k0 == 24);

    float partial[4] = {0.f, 0.f, 0.f, 0.f};

    for (int j0 = 0; j0 < NA; j0 += 16) {
        const int j = j0 + l15;
        // A-frag from LDS: dword base j*30+k0 is even -> 8B-aligned ds_read_b64
        const float* __restrict__ ep = elds + j*EF + k0;
        const float2 v0 = *reinterpret_cast<const float2*>(ep + 0);
        const float2 v1 = *reinterpret_cast<const float2*>(ep + 2);
        const float2 v2 = *reinterpret_cast<const float2*>(ep + 4);
        const float2 vt = *reinterpret_cast<const float2*>(ep + (ktail ? 4 : 6));
        const float v6 = ktail ? 0.f : vt.x;
        const float v7 = ktail ? 0.f : vt.y;
        bf16x8 Af;
        Af[0] = f2s16(v0.x); Af[1] = f2s16(v0.y);
        Af[2] = f2s16(v1.x); Af[3] = f2s16(v1.y);
        Af[4] = f2s16(v2.x); Af[5] = f2s16(v2.y);
        Af[6] = f2s16(v6);   Af[7] = f2s16(v7);

        const int jr = j0 + lq*4;           // this lane's first D-row
        float emv[4];
#pragma unroll
        for (int r = 0; r < 4; ++r) emv[r] = em_row[jr + r];

#pragma unroll
        for (int n = 0; n < 4; ++n) {
            f32x4 acc = {bias[n], bias[n], bias[n], bias[n]};
            acc = __builtin_amdgcn_mfma_f32_16x16x32_bf16(Af, Bf[n], acc, 0, 0, 0);
            const int f = (wid*4 + n)*16 + l15;
#pragma unroll
            for (int r = 0; r < 4; ++r) {
                const float efv = selu_f(acc[r]) * emv[r];
                partial[n] = fmaf(hb[(jr + r)*HD + f], efv, partial[n]);
            }
        }
    }

#pragma unroll
    for (int n = 0; n < 4; ++n) {
        partial[n] += __shfl_xor(partial[n], 16);
        partial[n] += __shfl_xor(partial[n], 32);
    }
    if (lane < 16) {
#pragma unroll
        for (int n = 0; n < 4; ++n) {
            const int f = (wid*4 + n)*16 + lane;
            // A-frag layout: m=bi>>4, s=f>>5, lane'=((f>>3)&3)*16+(bi&15), e=f&7
            const int idx = ((((bi >> 4)*8 + (f >> 5))*64) + ((f >> 3) & 3)*16 + (bi & 15))*8 + (f & 7);
            h1A[idx] = f2u16(partial[n]);
        }
    }
}

// -----------------------------------------------------------------------------
// Stage 2: out = selu(concat(h,h1) @ Ww^T + bw) * node_mask + h.
// One wave per (16-row M-tile, 16-col N-tile): 2048 waves, 512 blocks.
// All operands pre-swizzled: A from hA (s<8) / h1A (s>=8), B from WwFrag —
// every K-step is two coalesced 16B loads + one MFMA. No LDS, no barriers.
// -----------------------------------------------------------------------------
__global__ __launch_bounds__(256)
void efconv_stage2(const float* __restrict__ h, const bf16x8* __restrict__ hA,
                   const bf16x8* __restrict__ h1A, const float* __restrict__ nm,
                   const float* __restrict__ bw, const bf16x8* __restrict__ WwFrag,
                   float* __restrict__ out)
{
    const int tid  = threadIdx.x;
    const int lane = tid & 63;
    const int wid  = tid >> 6;
    const int wgid = blockIdx.x*4 + wid;   // 0..2047
    const int m    = wgid >> 4;            // M-tile 0..127
    const int t    = wgid & 15;            // N-tile 0..15
    const int l15  = lane & 15;
    const int lq   = lane >> 4;

    const float biasv = bw[t*16 + l15];
    f32x4 acc = {biasv, biasv, biasv, biasv};

#pragma unroll
    for (int s = 0; s < 8; ++s) {          // z = h (k < 256)
        const bf16x8 Af  = hA[(m*8 + s)*64 + lane];
        const bf16x8 Bfr = WwFrag[(t*16 + s)*64 + lane];
        acc = __builtin_amdgcn_mfma_f32_16x16x32_bf16(Af, Bfr, acc, 0, 0, 0);
    }
#pragma unroll
    for (int s = 0; s < 8; ++s) {          // z = h1 (k >= 256)
        const bf16x8 Af  = h1A[(m*8 + s)*64 + lane];
        const bf16x8 Bfr = WwFrag[(t*16 + s + 8)*64 + lane];
        acc = __builtin_amdgcn_mfma_f32_16x16x32_bf16(Af, Bfr, acc, 0, 0, 0);
    }

    const int f = t*16 + l15;
#pragma unroll
    for (int r = 0; r < 4; ++r) {
        const int bi = m*16 + lq*4 + r;
        const float v = selu_f(acc[r]);
        out[(size_t)bi*HD + f] = fmaf(v, nm[bi], h[(size_t)bi*HD + f]);
    }
}

// -----------------------------------------------------------------------------
// Launch. Inputs: h, e, node_mask, edge_mask, Wf, bf, Ww, bw.
// -----------------------------------------------------------------------------
extern "C" void kernel_launch(void* const* d_in, const int* in_sizes, int n_in,
                              void* d_out, int out_size, void* d_ws, size_t ws_size,
                              hipStream_t stream)
{
    (void)in_sizes; (void)n_in; (void)out_size; (void)ws_size;
    const float* h  = (const float*)d_in[0];
    const float* e  = (const float*)d_in[1];
    const float* nm = (const float*)d_in[2];
    const float* em = (const float*)d_in[3];
    const float* Wf = (const float*)d_in[4];
    const float* bf = (const float*)d_in[5];
    const float* Ww = (const float*)d_in[6];
    const float* bw = (const float*)d_in[7];
    float* out = (float*)d_out;

    unsigned short* h1A     = (unsigned short*)d_ws;
    unsigned short* WfFragU = (unsigned short*)((char*)d_ws + (1u << 20));
    unsigned short* WwFragU = (unsigned short*)((char*)d_ws + (1u << 20) + (16u << 10));
    unsigned short* hAU     = (unsigned short*)((char*)d_ws + (1u << 20) + (272u << 10));

    // total prep elements: 8192 + 131072 + 524288 = 663552 -> 2592 blocks
    hipLaunchKernelGGL(efconv_prep, dim3(2592), dim3(256), 0, stream,
                       Wf, Ww, h, WfFragU, WwFragU, hAU);
    hipLaunchKernelGGL(efconv_stage1, dim3(NB * NA), dim3(256), 0, stream,
                       e, h, em, bf, (const bf16x8*)WfFragU, h1A);
    hipLaunchKernelGGL(efconv_stage2, dim3(512), dim3(256), 0, stream,
                       h, (const bf16x8*)hAU, (const bf16x8*)h1A, nm, bw,
                       (const bf16x8*)WwFragU, out);
}